// Round 2
// baseline (868.629 us; speedup 1.0000x reference)
//
#include <hip/hip_runtime.h>
#include <hip/hip_bf16.h>

#define HH 352
#define WW 1216
#define HWSZ (HH * WW)   // 428032
#define TT 6

// ---------------- workspace layout (in floats) ----------------
// [0]                : int mode flag (1 = bf16 inputs, 0 = fp32 inputs)
// [16 .. 16+10950)   : repacked conv weights, per t: 25 bias + 72*25 weights (stride 1825)
// [11008 .. +876)    : tail weights (fp32)
// [12032 .. +7*HW)   : feature planes: t=0..5 outputs, index 6 = converted feat_init
// then: a1_22 (22*HW), a11 (11*HW), a21 (11*HW), agg (2*HW)
#define WS_CW   16
#define WS_TW   11008
#define WS_FB   12032

__device__ inline float ld_in(const void* p, long long i, int bf) {
    return bf ? __bfloat162float(((const __hip_bfloat16*)p)[i]) : ((const float*)p)[i];
}

// ---------------- prep: dtype detect + weight repack ----------------
__global__ void prep_small(const void* guid,
                           const void* aww, const void* awb, const void* aow, const void* aob,
                           const void* projw, const void* bng, const void* bnb,
                           const void* bnm, const void* bnv,
                           const void* l0w, const void* l0b, const void* lsw, const void* lsb,
                           const void* l1w, const void* l1b, const void* l2w, const void* l2b,
                           const void* sqw, const void* sqb, const void* lcw, const void* lcb,
                           float* ws) {
    __shared__ int smode;
    const int tid = threadIdx.x;
    if (tid == 0) {
        const unsigned int* u = (const unsigned int*)guid;
        int cnt = 0;
        for (int i = 0; i < 128; ++i) {
            unsigned int lo = u[i] & 0xFFFFu;
            int e = (int)((lo >> 7) & 0xFF);
            if (e >= 110 && e <= 140) cnt++;
        }
        int mode = (cnt >= 96) ? 1 : 0;
        smode = mode;
        *(int*)ws = mode;
    }
    __syncthreads();
    const int bf = smode;
    float* cw = ws + WS_CW;
    // aff weights: (T,9,8,3,3) -> cw[t*1825 + 25 + (ci*9+tap)*25 + co]
    for (int idx = tid; idx < TT * 9 * 72; idx += blockDim.x) {
        int t = idx / (9 * 72); int r = idx % (9 * 72);
        int co = r / 72; int ci = (r % 72) / 9; int tap = r % 9;
        cw[t * 1825 + 25 + (ci * 9 + tap) * 25 + co] = ld_in(aww, idx, bf);
    }
    // off weights: (T,16,8,3,3) -> position 9+co
    for (int idx = tid; idx < TT * 16 * 72; idx += blockDim.x) {
        int t = idx / (16 * 72); int r = idx % (16 * 72);
        int co = r / 72; int ci = (r % 72) / 9; int tap = r % 9;
        cw[t * 1825 + 25 + (ci * 9 + tap) * 25 + 9 + co] = ld_in(aow, idx, bf);
    }
    for (int idx = tid; idx < TT * 9; idx += blockDim.x)
        cw[(idx / 9) * 1825 + (idx % 9)] = ld_in(awb, idx, bf);
    for (int idx = tid; idx < TT * 16; idx += blockDim.x)
        cw[(idx / 16) * 1825 + 9 + (idx % 16)] = ld_in(aob, idx, bf);

    float* tw = ws + WS_TW;
    for (int i = tid; i < 18; i += blockDim.x) tw[i] = ld_in(projw, i, bf);
    for (int i = tid; i < 6; i += blockDim.x) {
        float sc = ld_in(bng, i, bf) * rsqrtf(ld_in(bnv, i, bf) + 1e-5f);
        tw[18 + i] = sc;
        tw[24 + i] = ld_in(bnb, i, bf) - ld_in(bnm, i, bf) * sc;
    }
    for (int i = tid; i < 22;  i += blockDim.x) tw[32  + i] = ld_in(l0w, i, bf);
    for (int i = tid; i < 22;  i += blockDim.x) tw[54  + i] = ld_in(l0b, i, bf);
    for (int i = tid; i < 198; i += blockDim.x) tw[76  + i] = ld_in(lsw, i, bf);
    for (int i = tid; i < 22;  i += blockDim.x) tw[274 + i] = ld_in(lsb, i, bf);
    for (int i = tid; i < 242; i += blockDim.x) tw[296 + i] = ld_in(l1w, i, bf);
    for (int i = tid; i < 11;  i += blockDim.x) tw[538 + i] = ld_in(l1b, i, bf);
    for (int i = tid; i < 242; i += blockDim.x) tw[549 + i] = ld_in(l2w, i, bf);
    for (int i = tid; i < 11;  i += blockDim.x) tw[791 + i] = ld_in(l2b, i, bf);
    for (int i = tid; i < 36;  i += blockDim.x) tw[802 + i] = ld_in(sqw, i, bf);
    for (int i = tid; i < 2;   i += blockDim.x) tw[838 + i] = ld_in(sqb, i, bf);
    for (int i = tid; i < 33;  i += blockDim.x) tw[840 + i] = ld_in(lcw, i, bf);
    for (int i = tid; i < 3;   i += blockDim.x) tw[873 + i] = ld_in(lcb, i, bf);
}

__global__ void prep_feat(const void* __restrict__ feat_init, const int* __restrict__ flagp,
                          float* __restrict__ dst) {
    int bf = *flagp;
    int i = blockIdx.x * 256 + threadIdx.x;
    if (i < HWSZ) dst[i] = ld_in(feat_init, i, bf);
}

// ---------------- fused conv + deformable sampling step ----------------
__device__ inline float samp(const float* __restrict__ src, int y, int x) {
    bool valid = (y >= 0) & (y < HH) & (x >= 0) & (x < WW);
    int yc = min(max(y, 0), HH - 1);
    int xc = min(max(x, 0), WW - 1);
    float v = src[yc * WW + xc];
    return valid ? v : 0.0f;
}

__global__ __launch_bounds__(256) void dcn_step(
        const void* __restrict__ guid, const int* __restrict__ flagp,
        const float* __restrict__ wts,          // 25 bias then 72*25 weights
        const float* __restrict__ src, float* __restrict__ dst, int t) {
    __shared__ float g[8][10][34];
    const int bf = *flagp;
    const int bx = blockIdx.x % 38, by = blockIdx.x / 38;
    const int x0 = bx * 32, y0 = by * 8;
    const int plane0 = t * 8;
    for (int idx = threadIdx.x; idx < 8 * 340; idx += 256) {
        int ci = idx / 340; int r = (idx % 340) / 34; int c = idx % 34;
        int gy = y0 - 1 + r, gx = x0 - 1 + c;
        float v = 0.0f;
        if (gy >= 0 && gy < HH && gx >= 0 && gx < WW)
            v = ld_in(guid, (long long)(plane0 + ci) * HWSZ + gy * WW + gx, bf);
        g[ci][r][c] = v;
    }
    __syncthreads();
    const int lx = threadIdx.x % 32, ly = threadIdx.x / 32;

    float acc[25];
#pragma unroll
    for (int co = 0; co < 25; ++co) acc[co] = wts[co];
    const float* wp = wts + 25;
#pragma unroll
    for (int ci = 0; ci < 8; ++ci) {
        float gv[9];
#pragma unroll
        for (int dy = 0; dy < 3; ++dy)
#pragma unroll
            for (int dx = 0; dx < 3; ++dx)
                gv[dy * 3 + dx] = g[ci][ly + dy][lx + dx];
#pragma unroll
        for (int tap = 0; tap < 9; ++tap) {
            const float* wr = wp + (ci * 9 + tap) * 25;
#pragma unroll
            for (int co = 0; co < 25; ++co)
                acc[co] = fmaf(gv[tap], wr[co], acc[co]);
        }
    }
    // affinity: sigmoid + normalize
    float w9[9]; float s = 0.0f;
#pragma unroll
    for (int k = 0; k < 9; ++k) { w9[k] = 1.0f / (1.0f + __expf(-acc[k])); s += w9[k]; }
    const float inv = 1.0f / (s + 1e-8f);

    const int gy = y0 + ly, gx = x0 + lx;
    float out = 0.0f;
#pragma unroll
    for (int k = 0; k < 9; ++k) {
        float oy, ox;
        if (k == 4) { oy = 0.0f; ox = 0.0f; }
        else { int kp = (k < 4) ? k : (k - 1); oy = acc[9 + 2 * kp]; ox = acc[9 + 2 * kp + 1]; }
        float ys = (float)gy + (float)(k / 3 - 1) + oy;
        float xs = (float)gx + (float)(k % 3 - 1) + ox;
        float yf = floorf(ys), xf = floorf(xs);
        float wy = ys - yf, wx = xs - xf;
        int yi = (int)yf, xi = (int)xf;
        float v00 = samp(src, yi, xi);
        float v01 = samp(src, yi, xi + 1);
        float v10 = samp(src, yi + 1, xi);
        float v11 = samp(src, yi + 1, xi + 1);
        float sv = v00 * (1.0f - wy) * (1.0f - wx) + v01 * (1.0f - wy) * wx
                 + v10 * wy * (1.0f - wx) + v11 * wy * wx;
        out = fmaf(w9[k] * inv, sv, out);
    }
    dst[gy * WW + gx] = out;
}

// ---------------- tail ----------------
__global__ __launch_bounds__(256) void tail1(
        const void* __restrict__ attn, const int* __restrict__ flagp,
        const float* __restrict__ tw, const float* __restrict__ feats,
        float* __restrict__ a1) {
    const int bf = *flagp;
    const int p = blockIdx.x * 256 + threadIdx.x;
    float x3[3] = { feats[3 * HWSZ + p], feats[4 * HWSZ + p], feats[5 * HWSZ + p] };
    float sf[6];
#pragma unroll
    for (int j = 0; j < 6; ++j) {
        float v = tw[j * 3 + 0] * x3[0] + tw[j * 3 + 1] * x3[1] + tw[j * 3 + 2] * x3[2];
        v = v * tw[18 + j] + tw[24 + j];
        sf[j] = (v >= 0.0f) ? v : 0.2f * v;
    }
#pragma unroll
    for (int c = 0; c < 22; ++c) {
        float x = (c < 16) ? ld_in(attn, (long long)c * HWSZ + p, bf) : sf[c - 16];
        a1[c * HWSZ + p] = fmaf(x, tw[32 + c], tw[54 + c]);
    }
}

__global__ __launch_bounds__(256) void tail2(
        const float* __restrict__ tw, const float* __restrict__ a1,
        float* __restrict__ a11, float* __restrict__ a21, float* __restrict__ agg) {
    __shared__ float tile[10][34];
    const int bx = blockIdx.x % 38, by = blockIdx.x / 38;
    const int x0 = bx * 32, y0 = by * 8;
    const int lx = threadIdx.x % 32, ly = threadIdx.x / 32;
    float acc1[11], acc2[11];
#pragma unroll
    for (int j = 0; j < 11; ++j) { acc1[j] = tw[538 + j]; acc2[j] = tw[791 + j]; }
    for (int c = 0; c < 22; ++c) {
        __syncthreads();
        for (int idx = threadIdx.x; idx < 340; idx += 256) {
            int r = idx / 34, cc = idx % 34;
            int gy = y0 - 1 + r, gx = x0 - 1 + cc;
            tile[r][cc] = (gy >= 0 && gy < HH && gx >= 0 && gx < WW)
                          ? a1[c * HWSZ + gy * WW + gx] : 0.0f;
        }
        __syncthreads();
        float a1c = tile[ly + 1][lx + 1];
        float a2c = tw[274 + c];
#pragma unroll
        for (int dy = 0; dy < 3; ++dy)
#pragma unroll
            for (int dx = 0; dx < 3; ++dx)
                a2c = fmaf(tile[ly + dy][lx + dx], tw[76 + c * 9 + dy * 3 + dx], a2c);
#pragma unroll
        for (int j = 0; j < 11; ++j) {
            acc1[j] = fmaf(a1c, tw[296 + j * 22 + c], acc1[j]);
            acc2[j] = fmaf(a2c, tw[549 + j * 22 + c], acc2[j]);
        }
    }
    const int p = (y0 + ly) * WW + x0 + lx;
    float s = 0.0f, mx = -1e30f;
#pragma unroll
    for (int j = 0; j < 11; ++j) {
        a11[j * HWSZ + p] = acc1[j];
        a21[j * HWSZ + p] = acc2[j];
        s += acc1[j] + acc2[j];
        mx = fmaxf(mx, fmaxf(acc1[j], acc2[j]));
    }
    agg[p] = s * (1.0f / 22.0f);
    agg[HWSZ + p] = mx;
}

__global__ __launch_bounds__(256) void tail3(
        const int* __restrict__ flagp, const float* __restrict__ tw,
        const float* __restrict__ feats,
        const float* __restrict__ a11, const float* __restrict__ a21,
        const float* __restrict__ agg, void* __restrict__ out) {
    __shared__ float t0[10][34], t1[10][34];
    const int bx = blockIdx.x % 38, by = blockIdx.x / 38;
    const int x0 = bx * 32, y0 = by * 8;
    for (int idx = threadIdx.x; idx < 340; idx += 256) {
        int r = idx / 34, cc = idx % 34;
        int gy = y0 - 1 + r, gx = x0 - 1 + cc;
        bool ok = (gy >= 0 && gy < HH && gx >= 0 && gx < WW);
        t0[r][cc] = ok ? agg[gy * WW + gx] : 0.0f;
        t1[r][cc] = ok ? agg[HWSZ + gy * WW + gx] : 0.0f;
    }
    __syncthreads();
    const int lx = threadIdx.x % 32, ly = threadIdx.x / 32;
    float s0 = tw[838], s1 = tw[839];
#pragma unroll
    for (int dy = 0; dy < 3; ++dy)
#pragma unroll
        for (int dx = 0; dx < 3; ++dx) {
            float v0 = t0[ly + dy][lx + dx], v1 = t1[ly + dy][lx + dx];
            s0 = fmaf(v0, tw[802 + 0 * 18 + 0 * 9 + dy * 3 + dx], s0);
            s0 = fmaf(v1, tw[802 + 0 * 18 + 1 * 9 + dy * 3 + dx], s0);
            s1 = fmaf(v0, tw[802 + 1 * 18 + 0 * 9 + dy * 3 + dx], s1);
            s1 = fmaf(v1, tw[802 + 1 * 18 + 1 * 9 + dy * 3 + dx], s1);
        }
    float sg0 = 1.0f / (1.0f + __expf(-s0));
    float sg1 = 1.0f / (1.0f + __expf(-s1));
    const int p = (y0 + ly) * WW + x0 + lx;
    float at3[3] = { tw[873], tw[874], tw[875] };
#pragma unroll
    for (int j = 0; j < 11; ++j) {
        float at = a11[j * HWSZ + p] * sg0 + a21[j * HWSZ + p] * sg1;
#pragma unroll
        for (int i = 0; i < 3; ++i) at3[i] = fmaf(at, tw[840 + i * 11 + j], at3[i]);
    }
    float o = feats[3 * HWSZ + p] * at3[0] + feats[4 * HWSZ + p] * at3[1]
            + feats[5 * HWSZ + p] * at3[2];
    int bf = *flagp;
    if (bf) ((__hip_bfloat16*)out)[p] = __float2bfloat16(o);
    else    ((float*)out)[p] = o;
}

// ---------------- host ----------------
extern "C" void kernel_launch(void* const* d_in, const int* in_sizes, int n_in,
                              void* d_out, int out_size, void* d_ws, size_t ws_size,
                              hipStream_t stream) {
    (void)in_sizes; (void)n_in; (void)out_size; (void)ws_size;
    float* WSF = (float*)d_ws;
    const int* flagp = (const int*)d_ws;
    float* cw  = WSF + WS_CW;
    float* tw  = WSF + WS_TW;
    float* FB  = WSF + WS_FB;            // 7 planes of HWSZ
    float* A1  = FB + 7 * HWSZ;          // 22 planes
    float* A11 = A1 + 22 * HWSZ;         // 11 planes
    float* A21 = A11 + 11 * HWSZ;        // 11 planes
    float* AGG = A21 + 11 * HWSZ;        // 2 planes

    prep_small<<<1, 256, 0, stream>>>(d_in[1],
        d_in[4], d_in[5], d_in[6], d_in[7],
        d_in[8], d_in[9], d_in[10], d_in[11], d_in[12],
        d_in[13], d_in[14], d_in[15], d_in[16],
        d_in[17], d_in[18], d_in[19], d_in[20],
        d_in[21], d_in[22], d_in[23], d_in[24], WSF);
    prep_feat<<<(HWSZ + 255) / 256, 256, 0, stream>>>(d_in[0], flagp, FB + 6 * HWSZ);

    for (int t = 0; t < 6; ++t) {
        const float* src = (t == 0) ? (FB + 6 * HWSZ) : (FB + (t - 1) * HWSZ);
        dcn_step<<<44 * 38, 256, 0, stream>>>(d_in[1], flagp, cw + t * 1825, src, FB + t * HWSZ, t);
    }
    tail1<<<HWSZ / 256, 256, 0, stream>>>(d_in[2], flagp, tw, FB, A1);
    tail2<<<44 * 38, 256, 0, stream>>>(tw, A1, A11, A21, AGG);
    tail3<<<44 * 38, 256, 0, stream>>>(flagp, tw, FB, A11, A21, AGG, d_out);
}

// Round 3
// 622.829 us; speedup vs baseline: 1.3946x; 1.3946x over previous
//
#include <hip/hip_runtime.h>
#include <hip/hip_bf16.h>

#define HH 352
#define WW 1216
#define HWSZ (HH * WW)   // 428032
#define TT 6

// ---------------- workspace layout (in floats) ----------------
// [0]            : int mode flag (1 = bf16 inputs, 0 = fp32 inputs)
// [16 ..)        : repacked conv weights, per t: 25 bias + 25*72 weights (stride 1825)
// [11008 ..)     : tail weights
// [12032 ..)     : OFF planes [25][HWSZ] (9 normalized affinities, 16 offsets)
// then           : FB 7 planes, A1 22, A11 11, A21 11, AGG 2
#define WS_CW   16
#define WS_TW   11008
#define WS_OFF  12032

typedef __attribute__((ext_vector_type(4))) float f32x4;
typedef __attribute__((ext_vector_type(8))) short s16x8;
union FU { unsigned int u[4]; s16x8 v; };

__device__ inline float ld_in(const void* p, long long i, int bf) {
    return bf ? __bfloat162float(((const __hip_bfloat16*)p)[i]) : ((const float*)p)[i];
}

// split v into bf16 hi (low16) + bf16 lo (high16), RNE
__device__ inline unsigned int bfsplit_pack(float v) {
    unsigned int uv = __float_as_uint(v);
    unsigned int h = (uv + 0x7FFFu + ((uv >> 16) & 1u)) >> 16;
    float hf = __uint_as_float(h << 16);
    float r = v - hf;
    unsigned int ur = __float_as_uint(r);
    unsigned int l = (ur + 0x7FFFu + ((ur >> 16) & 1u)) >> 16;
    return (h & 0xFFFFu) | (l << 16);
}

// ---------------- prep: dtype detect + weight repack ----------------
__global__ void prep_small(const void* guid,
                           const void* aww, const void* awb, const void* aow, const void* aob,
                           const void* projw, const void* bng, const void* bnb,
                           const void* bnm, const void* bnv,
                           const void* l0w, const void* l0b, const void* lsw, const void* lsb,
                           const void* l1w, const void* l1b, const void* l2w, const void* l2b,
                           const void* sqw, const void* sqb, const void* lcw, const void* lcb,
                           float* ws) {
    __shared__ int smode;
    const int tid = threadIdx.x;
    if (tid == 0) {
        const unsigned int* u = (const unsigned int*)guid;
        int cnt = 0;
        for (int i = 0; i < 128; ++i) {
            unsigned int lo = u[i] & 0xFFFFu;
            int e = (int)((lo >> 7) & 0xFF);
            if (e >= 110 && e <= 140) cnt++;
        }
        int mode = (cnt >= 96) ? 1 : 0;
        smode = mode;
        *(int*)ws = mode;
    }
    __syncthreads();
    const int bf = smode;
    float* cw = ws + WS_CW;
    // aff weights (T,9,8,3,3) -> cw[t*1825 + 25 + co*72 + ci*9 + tap]
    for (int idx = tid; idx < TT * 9 * 72; idx += blockDim.x) {
        int t = idx / 648; int r = idx % 648;
        int co = r / 72; int ci = (r % 72) / 9; int tap = r % 9;
        cw[t * 1825 + 25 + co * 72 + ci * 9 + tap] = ld_in(aww, idx, bf);
    }
    // off weights (T,16,8,3,3) -> co' = 9+co
    for (int idx = tid; idx < TT * 16 * 72; idx += blockDim.x) {
        int t = idx / 1152; int r = idx % 1152;
        int co = r / 72; int ci = (r % 72) / 9; int tap = r % 9;
        cw[t * 1825 + 25 + (9 + co) * 72 + ci * 9 + tap] = ld_in(aow, idx, bf);
    }
    for (int idx = tid; idx < TT * 9; idx += blockDim.x)
        cw[(idx / 9) * 1825 + (idx % 9)] = ld_in(awb, idx, bf);
    for (int idx = tid; idx < TT * 16; idx += blockDim.x)
        cw[(idx / 16) * 1825 + 9 + (idx % 16)] = ld_in(aob, idx, bf);

    float* tw = ws + WS_TW;
    for (int i = tid; i < 18; i += blockDim.x) tw[i] = ld_in(projw, i, bf);
    for (int i = tid; i < 6; i += blockDim.x) {
        float sc = ld_in(bng, i, bf) * rsqrtf(ld_in(bnv, i, bf) + 1e-5f);
        tw[18 + i] = sc;
        tw[24 + i] = ld_in(bnb, i, bf) - ld_in(bnm, i, bf) * sc;
    }
    for (int i = tid; i < 22;  i += blockDim.x) tw[32  + i] = ld_in(l0w, i, bf);
    for (int i = tid; i < 22;  i += blockDim.x) tw[54  + i] = ld_in(l0b, i, bf);
    for (int i = tid; i < 198; i += blockDim.x) tw[76  + i] = ld_in(lsw, i, bf);
    for (int i = tid; i < 22;  i += blockDim.x) tw[274 + i] = ld_in(lsb, i, bf);
    for (int i = tid; i < 242; i += blockDim.x) tw[296 + i] = ld_in(l1w, i, bf);
    for (int i = tid; i < 11;  i += blockDim.x) tw[538 + i] = ld_in(l1b, i, bf);
    for (int i = tid; i < 242; i += blockDim.x) tw[549 + i] = ld_in(l2w, i, bf);
    for (int i = tid; i < 11;  i += blockDim.x) tw[791 + i] = ld_in(l2b, i, bf);
    for (int i = tid; i < 36;  i += blockDim.x) tw[802 + i] = ld_in(sqw, i, bf);
    for (int i = tid; i < 2;   i += blockDim.x) tw[838 + i] = ld_in(sqb, i, bf);
    for (int i = tid; i < 33;  i += blockDim.x) tw[840 + i] = ld_in(lcw, i, bf);
    for (int i = tid; i < 3;   i += blockDim.x) tw[873 + i] = ld_in(lcb, i, bf);
}

__global__ void prep_feat(const void* __restrict__ feat_init, const int* __restrict__ flagp,
                          float* __restrict__ dst) {
    int bf = *flagp;
    int i = blockIdx.x * 256 + threadIdx.x;
    if (i < HWSZ) dst[i] = ld_in(feat_init, i, bf);
}

// ---------------- MFMA implicit-GEMM conv (25ch out of 8ch 3x3) ----------------
// K-chunk c = dy; within chunk k = (g,j): ci = 2g + (j>>2), dx = j&3 (dx==3 is a
// zero-weight pad). Any consistent k-permutation of A and B is valid; only the
// C/D layout (col=lane&15, row=(lane>>4)*4+reg) must match HW, which is verified.
__global__ __launch_bounds__(256) void conv_mfma(
        const void* __restrict__ guid, const int* __restrict__ flagp,
        const float* __restrict__ wts, float* __restrict__ OFF, int t) {
    __shared__ unsigned int hal[8][10][36];   // (hi|lo<<16) packed bf16 pair
    __shared__ float outb[4][64][33];         // per-wave redistribution buffer
    const int bf = *flagp;
    const int bx = blockIdx.x % 38, by = blockIdx.x / 38;
    const int x0 = bx * 32, y0 = by * 8;
    for (int idx = threadIdx.x; idx < 8 * 360; idx += 256) {
        int ci = idx / 360; int r = (idx % 360) / 36; int c = idx % 36;
        int gy = y0 - 1 + r, gx = x0 - 1 + c;
        float v = 0.f;
        if (c < 34 && gy >= 0 && gy < HH && gx >= 0 && gx < WW)
            v = ld_in(guid, (long long)(t * 8 + ci) * HWSZ + gy * WW + gx, bf);
        hal[ci][r][c] = bfsplit_pack(v);
    }
    const int lane = threadIdx.x & 63;
    const int wave = threadIdx.x >> 6;
    const int col = lane & 15, g = lane >> 4;

    // B fragments (weights), built once: Bh/Bl[Ntile][chunk]
    FU Bh[2][3], Bl[2][3];
#pragma unroll
    for (int Nt = 0; Nt < 2; ++Nt)
#pragma unroll
    for (int c = 0; c < 3; ++c) {
        unsigned short eh[8], el[8];
#pragma unroll
        for (int j = 0; j < 8; ++j) {
            int ci = 2 * g + (j >> 2), dx = j & 3;
            int cc = Nt * 16 + col;
            float w = 0.f;
            if (cc < 25 && dx < 3) w = wts[25 + cc * 72 + ci * 9 + c * 3 + dx];
            unsigned int pk = bfsplit_pack(w);
            eh[j] = (unsigned short)(pk & 0xFFFFu);
            el[j] = (unsigned short)(pk >> 16);
        }
#pragma unroll
        for (int q = 0; q < 4; ++q) {
            Bh[Nt][c].u[q] = (unsigned int)eh[2*q] | ((unsigned int)eh[2*q+1] << 16);
            Bl[Nt][c].u[q] = (unsigned int)el[2*q] | ((unsigned int)el[2*q+1] << 16);
        }
    }
    __syncthreads();

    const float* bias = wts;
#pragma unroll
    for (int m = 0; m < 4; ++m) {
        const int M = wave * 4 + m;
        const int py = M >> 1;
        const int pxx = (M & 1) * 16 + col;    // this lane's A-row pixel
        FU Ah[3], Al[3];
#pragma unroll
        for (int c = 0; c < 3; ++c) {
            const unsigned int* r0 = &hal[2 * g][py + c][pxx];
            const unsigned int* r1 = &hal[2 * g + 1][py + c][pxx];
            unsigned int q0 = r0[0], q1 = r0[1], q2 = r0[2], q3 = r0[3];
            unsigned int q4 = r1[0], q5 = r1[1], q6 = r1[2], q7 = r1[3];
            Ah[c].u[0] = __builtin_amdgcn_perm(q1, q0, 0x05040100u);
            Ah[c].u[1] = __builtin_amdgcn_perm(q3, q2, 0x05040100u);
            Ah[c].u[2] = __builtin_amdgcn_perm(q5, q4, 0x05040100u);
            Ah[c].u[3] = __builtin_amdgcn_perm(q7, q6, 0x05040100u);
            Al[c].u[0] = __builtin_amdgcn_perm(q1, q0, 0x07060302u);
            Al[c].u[1] = __builtin_amdgcn_perm(q3, q2, 0x07060302u);
            Al[c].u[2] = __builtin_amdgcn_perm(q5, q4, 0x07060302u);
            Al[c].u[3] = __builtin_amdgcn_perm(q7, q6, 0x07060302u);
        }
#pragma unroll
        for (int Nt = 0; Nt < 2; ++Nt) {
            f32x4 acc = {0.f, 0.f, 0.f, 0.f};
#pragma unroll
            for (int c = 0; c < 3; ++c) {
                acc = __builtin_amdgcn_mfma_f32_16x16x32_bf16(Ah[c].v, Bh[Nt][c].v, acc, 0, 0, 0);
                acc = __builtin_amdgcn_mfma_f32_16x16x32_bf16(Al[c].v, Bh[Nt][c].v, acc, 0, 0, 0);
                acc = __builtin_amdgcn_mfma_f32_16x16x32_bf16(Ah[c].v, Bl[Nt][c].v, acc, 0, 0, 0);
            }
            const int co = Nt * 16 + col;
            if (co < 25) {
                float bs = bias[co];
#pragma unroll
                for (int r = 0; r < 4; ++r)
                    outb[wave][m * 16 + g * 4 + r][co] = acc[r] + bs;
            }
        }
    }
    __syncthreads();
    // finalize: sigmoid+normalize affinities, write 25 SoA planes (coalesced)
    {
        const int pl = lane;
        const int Ml = pl >> 4, rd = pl & 15;
        const int M = wave * 4 + Ml;
        const int py = M >> 1;
        const int pxx = (M & 1) * 16 + rd;
        const int p = (y0 + py) * WW + x0 + pxx;
        float v[25];
#pragma unroll
        for (int c = 0; c < 25; ++c) v[c] = outb[wave][pl][c];
        float w9[9], s = 0.f;
#pragma unroll
        for (int k = 0; k < 9; ++k) { w9[k] = 1.f / (1.f + __expf(-v[k])); s += w9[k]; }
        float inv = 1.f / (s + 1e-8f);
#pragma unroll
        for (int k = 0; k < 9; ++k) OFF[k * HWSZ + p] = w9[k] * inv;
#pragma unroll
        for (int c = 9; c < 25; ++c) OFF[c * HWSZ + p] = v[c];
    }
}

// ---------------- light deformable-sampling step ----------------
__device__ inline float samp(const float* __restrict__ src, int y, int x) {
    bool valid = (y >= 0) & (y < HH) & (x >= 0) & (x < WW);
    int yc = min(max(y, 0), HH - 1);
    int xc = min(max(x, 0), WW - 1);
    float v = src[yc * WW + xc];
    return valid ? v : 0.0f;
}

__global__ __launch_bounds__(256) void sample_step(
        const float* __restrict__ OFF, const float* __restrict__ src,
        float* __restrict__ dst) {
    const int p = blockIdx.x * 256 + threadIdx.x;
    const int gy = p / WW, gx = p - gy * WW;
    float out = 0.f;
#pragma unroll
    for (int k = 0; k < 9; ++k) {
        float w = OFF[k * HWSZ + p];
        float oy = 0.f, ox = 0.f;
        if (k != 4) {
            int kp = (k < 4) ? k : (k - 1);
            oy = OFF[(9 + 2 * kp) * HWSZ + p];
            ox = OFF[(10 + 2 * kp) * HWSZ + p];
        }
        float ys = (float)(gy + k / 3 - 1) + oy;
        float xs = (float)(gx + k % 3 - 1) + ox;
        float yf = floorf(ys), xf = floorf(xs);
        float wy = ys - yf, wx = xs - xf;
        int yi = (int)yf, xi = (int)xf;
        float v00 = samp(src, yi, xi);
        float v01 = samp(src, yi, xi + 1);
        float v10 = samp(src, yi + 1, xi);
        float v11 = samp(src, yi + 1, xi + 1);
        float sv = v00 * (1.f - wy) * (1.f - wx) + v01 * (1.f - wy) * wx
                 + v10 * wy * (1.f - wx) + v11 * wy * wx;
        out = fmaf(w, sv, out);
    }
    dst[p] = out;
}

// ---------------- tail (unchanged from round 2) ----------------
__global__ __launch_bounds__(256) void tail1(
        const void* __restrict__ attn, const int* __restrict__ flagp,
        const float* __restrict__ tw, const float* __restrict__ feats,
        float* __restrict__ a1) {
    const int bf = *flagp;
    const int p = blockIdx.x * 256 + threadIdx.x;
    float x3[3] = { feats[3 * HWSZ + p], feats[4 * HWSZ + p], feats[5 * HWSZ + p] };
    float sf[6];
#pragma unroll
    for (int j = 0; j < 6; ++j) {
        float v = tw[j * 3 + 0] * x3[0] + tw[j * 3 + 1] * x3[1] + tw[j * 3 + 2] * x3[2];
        v = v * tw[18 + j] + tw[24 + j];
        sf[j] = (v >= 0.0f) ? v : 0.2f * v;
    }
#pragma unroll
    for (int c = 0; c < 22; ++c) {
        float x = (c < 16) ? ld_in(attn, (long long)c * HWSZ + p, bf) : sf[c - 16];
        a1[c * HWSZ + p] = fmaf(x, tw[32 + c], tw[54 + c]);
    }
}

__global__ __launch_bounds__(256) void tail2(
        const float* __restrict__ tw, const float* __restrict__ a1,
        float* __restrict__ a11, float* __restrict__ a21, float* __restrict__ agg) {
    __shared__ float tile[10][34];
    const int bx = blockIdx.x % 38, by = blockIdx.x / 38;
    const int x0 = bx * 32, y0 = by * 8;
    const int lx = threadIdx.x % 32, ly = threadIdx.x / 32;
    float acc1[11], acc2[11];
#pragma unroll
    for (int j = 0; j < 11; ++j) { acc1[j] = tw[538 + j]; acc2[j] = tw[791 + j]; }
    for (int c = 0; c < 22; ++c) {
        __syncthreads();
        for (int idx = threadIdx.x; idx < 340; idx += 256) {
            int r = idx / 34, cc = idx % 34;
            int gy = y0 - 1 + r, gx = x0 - 1 + cc;
            tile[r][cc] = (gy >= 0 && gy < HH && gx >= 0 && gx < WW)
                          ? a1[c * HWSZ + gy * WW + gx] : 0.0f;
        }
        __syncthreads();
        float a1c = tile[ly + 1][lx + 1];
        float a2c = tw[274 + c];
#pragma unroll
        for (int dy = 0; dy < 3; ++dy)
#pragma unroll
            for (int dx = 0; dx < 3; ++dx)
                a2c = fmaf(tile[ly + dy][lx + dx], tw[76 + c * 9 + dy * 3 + dx], a2c);
#pragma unroll
        for (int j = 0; j < 11; ++j) {
            acc1[j] = fmaf(a1c, tw[296 + j * 22 + c], acc1[j]);
            acc2[j] = fmaf(a2c, tw[549 + j * 22 + c], acc2[j]);
        }
    }
    const int p = (y0 + ly) * WW + x0 + lx;
    float s = 0.0f, mx = -1e30f;
#pragma unroll
    for (int j = 0; j < 11; ++j) {
        a11[j * HWSZ + p] = acc1[j];
        a21[j * HWSZ + p] = acc2[j];
        s += acc1[j] + acc2[j];
        mx = fmaxf(mx, fmaxf(acc1[j], acc2[j]));
    }
    agg[p] = s * (1.0f / 22.0f);
    agg[HWSZ + p] = mx;
}

__global__ __launch_bounds__(256) void tail3(
        const int* __restrict__ flagp, const float* __restrict__ tw,
        const float* __restrict__ feats,
        const float* __restrict__ a11, const float* __restrict__ a21,
        const float* __restrict__ agg, void* __restrict__ out) {
    __shared__ float t0[10][34], t1[10][34];
    const int bx = blockIdx.x % 38, by = blockIdx.x / 38;
    const int x0 = bx * 32, y0 = by * 8;
    for (int idx = threadIdx.x; idx < 340; idx += 256) {
        int r = idx / 34, cc = idx % 34;
        int gy = y0 - 1 + r, gx = x0 - 1 + cc;
        bool ok = (gy >= 0 && gy < HH && gx >= 0 && gx < WW);
        t0[r][cc] = ok ? agg[gy * WW + gx] : 0.0f;
        t1[r][cc] = ok ? agg[HWSZ + gy * WW + gx] : 0.0f;
    }
    __syncthreads();
    const int lx = threadIdx.x % 32, ly = threadIdx.x / 32;
    float s0 = tw[838], s1 = tw[839];
#pragma unroll
    for (int dy = 0; dy < 3; ++dy)
#pragma unroll
        for (int dx = 0; dx < 3; ++dx) {
            float v0 = t0[ly + dy][lx + dx], v1 = t1[ly + dy][lx + dx];
            s0 = fmaf(v0, tw[802 + 0 * 18 + 0 * 9 + dy * 3 + dx], s0);
            s0 = fmaf(v1, tw[802 + 0 * 18 + 1 * 9 + dy * 3 + dx], s0);
            s1 = fmaf(v0, tw[802 + 1 * 18 + 0 * 9 + dy * 3 + dx], s1);
            s1 = fmaf(v1, tw[802 + 1 * 18 + 1 * 9 + dy * 3 + dx], s1);
        }
    float sg0 = 1.0f / (1.0f + __expf(-s0));
    float sg1 = 1.0f / (1.0f + __expf(-s1));
    const int p = (y0 + ly) * WW + x0 + lx;
    float at3[3] = { tw[873], tw[874], tw[875] };
#pragma unroll
    for (int j = 0; j < 11; ++j) {
        float at = a11[j * HWSZ + p] * sg0 + a21[j * HWSZ + p] * sg1;
#pragma unroll
        for (int i = 0; i < 3; ++i) at3[i] = fmaf(at, tw[840 + i * 11 + j], at3[i]);
    }
    float o = feats[3 * HWSZ + p] * at3[0] + feats[4 * HWSZ + p] * at3[1]
            + feats[5 * HWSZ + p] * at3[2];
    int bf = *flagp;
    if (bf) ((__hip_bfloat16*)out)[p] = __float2bfloat16(o);
    else    ((float*)out)[p] = o;
}

// ---------------- host ----------------
extern "C" void kernel_launch(void* const* d_in, const int* in_sizes, int n_in,
                              void* d_out, int out_size, void* d_ws, size_t ws_size,
                              hipStream_t stream) {
    (void)in_sizes; (void)n_in; (void)out_size; (void)ws_size;
    float* WSF = (float*)d_ws;
    const int* flagp = (const int*)d_ws;
    float* cw   = WSF + WS_CW;
    float* tw   = WSF + WS_TW;
    float* OFFb = WSF + WS_OFF;            // 25 planes
    float* FB   = OFFb + 25 * HWSZ;        // 7 planes
    float* A1   = FB + 7 * HWSZ;           // 22 planes
    float* A11  = A1 + 22 * HWSZ;          // 11 planes
    float* A21  = A11 + 11 * HWSZ;         // 11 planes
    float* AGG  = A21 + 11 * HWSZ;         // 2 planes

    prep_small<<<1, 256, 0, stream>>>(d_in[1],
        d_in[4], d_in[5], d_in[6], d_in[7],
        d_in[8], d_in[9], d_in[10], d_in[11], d_in[12],
        d_in[13], d_in[14], d_in[15], d_in[16],
        d_in[17], d_in[18], d_in[19], d_in[20],
        d_in[21], d_in[22], d_in[23], d_in[24], WSF);
    prep_feat<<<(HWSZ + 255) / 256, 256, 0, stream>>>(d_in[0], flagp, FB + 6 * HWSZ);

    for (int t = 0; t < 6; ++t) {
        conv_mfma<<<44 * 38, 256, 0, stream>>>(d_in[1], flagp, cw + t * 1825, OFFb, t);
        const float* src = (t == 0) ? (FB + 6 * HWSZ) : (FB + (t - 1) * HWSZ);
        sample_step<<<44 * 38, 256, 0, stream>>>(OFFb, src, FB + t * HWSZ);
    }
    tail1<<<HWSZ / 256, 256, 0, stream>>>(d_in[2], flagp, tw, FB, A1);
    tail2<<<44 * 38, 256, 0, stream>>>(tw, A1, A11, A21, AGG);
    tail3<<<44 * 38, 256, 0, stream>>>(flagp, tw, FB, A11, A21, AGG, d_out);
}

// Round 4
// 484.442 us; speedup vs baseline: 1.7931x; 1.2857x over previous
//
#include <hip/hip_runtime.h>
#include <hip/hip_bf16.h>

#define HH 352
#define WW 1216
#define HWSZ (HH * WW)   // 428032
#define TT 6

// ---------------- workspace layout (in floats) ----------------
// [0]            : int mode flag (1 = bf16 inputs, 0 = fp32 inputs)
// [16 ..)        : repacked conv weights, per t: 25 bias + 25*72 weights (stride 1825)
// [11008 ..)     : tail weights
// [12032 ..)     : FB 7 planes (t=0..5 outputs, idx 6 = converted feat_init)
// then           : A1 22 planes, A11 11, A21 11, AGG 2
#define WS_CW   16
#define WS_TW   11008
#define WS_FB   12032

typedef __attribute__((ext_vector_type(4))) float f32x4;
typedef __attribute__((ext_vector_type(8))) short s16x8;
union FU { unsigned int u[4]; s16x8 v; };

__device__ inline float ld_in(const void* p, long long i, int bf) {
    return bf ? __bfloat162float(((const __hip_bfloat16*)p)[i]) : ((const float*)p)[i];
}

// split v into bf16 hi (low16) + bf16 lo (high16), RNE
__device__ inline unsigned int bfsplit_pack(float v) {
    unsigned int uv = __float_as_uint(v);
    unsigned int h = (uv + 0x7FFFu + ((uv >> 16) & 1u)) >> 16;
    float hf = __uint_as_float(h << 16);
    float r = v - hf;
    unsigned int ur = __float_as_uint(r);
    unsigned int l = (ur + 0x7FFFu + ((ur >> 16) & 1u)) >> 16;
    return (h & 0xFFFFu) | (l << 16);
}

__device__ inline int detect_mode(const void* guid) {
    const unsigned int* u = (const unsigned int*)guid;
    int cnt = 0;
    for (int i = 0; i < 128; ++i) {
        unsigned int lo = u[i] & 0xFFFFu;
        int e = (int)((lo >> 7) & 0xFF);
        if (e >= 110 && e <= 140) cnt++;
    }
    return (cnt >= 96) ? 1 : 0;
}

// ---------------- prep: dtype detect + weight repack (32 blocks) ----------------
__global__ void prep_small(const void* guid,
                           const void* aww, const void* awb, const void* aow, const void* aob,
                           const void* projw, const void* bng, const void* bnb,
                           const void* bnm, const void* bnv,
                           const void* l0w, const void* l0b, const void* lsw, const void* lsb,
                           const void* l1w, const void* l1b, const void* l2w, const void* l2b,
                           const void* sqw, const void* sqb, const void* lcw, const void* lcb,
                           float* ws) {
    __shared__ int smode;
    if (threadIdx.x == 0) {
        int mode = detect_mode(guid);
        smode = mode;
        if (blockIdx.x == 0) *(int*)ws = mode;
    }
    __syncthreads();
    const int bf = smode;
    const int tid = blockIdx.x * blockDim.x + threadIdx.x;
    const int stp = gridDim.x * blockDim.x;
    float* cw = ws + WS_CW;
    // aff weights (T,9,8,3,3) -> cw[t*1825 + 25 + co*72 + ci*9 + tap]
    for (int idx = tid; idx < TT * 9 * 72; idx += stp) {
        int t = idx / 648; int r = idx % 648;
        int co = r / 72; int ci = (r % 72) / 9; int tap = r % 9;
        cw[t * 1825 + 25 + co * 72 + ci * 9 + tap] = ld_in(aww, idx, bf);
    }
    // off weights (T,16,8,3,3) -> co' = 9+co
    for (int idx = tid; idx < TT * 16 * 72; idx += stp) {
        int t = idx / 1152; int r = idx % 1152;
        int co = r / 72; int ci = (r % 72) / 9; int tap = r % 9;
        cw[t * 1825 + 25 + (9 + co) * 72 + ci * 9 + tap] = ld_in(aow, idx, bf);
    }
    for (int idx = tid; idx < TT * 9; idx += stp)
        cw[(idx / 9) * 1825 + (idx % 9)] = ld_in(awb, idx, bf);
    for (int idx = tid; idx < TT * 16; idx += stp)
        cw[(idx / 16) * 1825 + 9 + (idx % 16)] = ld_in(aob, idx, bf);

    float* tw = ws + WS_TW;
    for (int i = tid; i < 18; i += stp) tw[i] = ld_in(projw, i, bf);
    for (int i = tid; i < 6; i += stp) {
        float sc = ld_in(bng, i, bf) * rsqrtf(ld_in(bnv, i, bf) + 1e-5f);
        tw[18 + i] = sc;
        tw[24 + i] = ld_in(bnb, i, bf) - ld_in(bnm, i, bf) * sc;
    }
    for (int i = tid; i < 22;  i += stp) tw[32  + i] = ld_in(l0w, i, bf);
    for (int i = tid; i < 22;  i += stp) tw[54  + i] = ld_in(l0b, i, bf);
    for (int i = tid; i < 198; i += stp) tw[76  + i] = ld_in(lsw, i, bf);
    for (int i = tid; i < 22;  i += stp) tw[274 + i] = ld_in(lsb, i, bf);
    for (int i = tid; i < 242; i += stp) tw[296 + i] = ld_in(l1w, i, bf);
    for (int i = tid; i < 11;  i += stp) tw[538 + i] = ld_in(l1b, i, bf);
    for (int i = tid; i < 242; i += stp) tw[549 + i] = ld_in(l2w, i, bf);
    for (int i = tid; i < 11;  i += stp) tw[791 + i] = ld_in(l2b, i, bf);
    for (int i = tid; i < 36;  i += stp) tw[802 + i] = ld_in(sqw, i, bf);
    for (int i = tid; i < 2;   i += stp) tw[838 + i] = ld_in(sqb, i, bf);
    for (int i = tid; i < 33;  i += stp) tw[840 + i] = ld_in(lcw, i, bf);
    for (int i = tid; i < 3;   i += stp) tw[873 + i] = ld_in(lcb, i, bf);
}

__global__ void prep_feat(const void* __restrict__ feat_init, const int* __restrict__ flagp,
                          float* __restrict__ dst) {
    int bf = *flagp;
    int i = blockIdx.x * 256 + threadIdx.x;
    if (i < HWSZ) dst[i] = ld_in(feat_init, i, bf);
}

// ---------------- fused MFMA conv + deformable sampling ----------------
__device__ inline float samp(const float* __restrict__ src, int y, int x) {
    bool valid = (y >= 0) & (y < HH) & (x >= 0) & (x < WW);
    int yc = min(max(y, 0), HH - 1);
    int xc = min(max(x, 0), WW - 1);
    float v = src[yc * WW + xc];
    return valid ? v : 0.0f;
}

// K-chunk c = dy; within chunk k = (g,j): ci = 2g + (j>>2), dx = j&3 (dx==3 pad).
// C/D layout: col(channel)=lane&15, row(pixel)=(lane>>4)*4+reg  (HW-verified).
__global__ __launch_bounds__(256) void dcn_fused(
        const void* __restrict__ guid, const int* __restrict__ flagp,
        const float* __restrict__ wts,
        const float* __restrict__ src, float* __restrict__ dst, int t) {
    __shared__ unsigned int hal[8][10][36];   // (hi|lo<<16) packed bf16 pair
    __shared__ float outb[4][64][27];         // per-wave redistribution buffer
    const int bf = *flagp;
    const int bx = blockIdx.x % 38, by = blockIdx.x / 38;
    const int x0 = bx * 32, y0 = by * 8;
    for (int idx = threadIdx.x; idx < 8 * 360; idx += 256) {
        int ci = idx / 360; int r = (idx % 360) / 36; int c = idx % 36;
        int gy = y0 - 1 + r, gx = x0 - 1 + c;
        float v = 0.f;
        if (c < 34 && gy >= 0 && gy < HH && gx >= 0 && gx < WW)
            v = ld_in(guid, (long long)(t * 8 + ci) * HWSZ + gy * WW + gx, bf);
        hal[ci][r][c] = bfsplit_pack(v);
    }
    const int lane = threadIdx.x & 63;
    const int wave = threadIdx.x >> 6;
    const int col = lane & 15, g = lane >> 4;

    // B fragments (weights): Bh/Bl[Ntile][chunk]
    FU Bh[2][3], Bl[2][3];
#pragma unroll
    for (int Nt = 0; Nt < 2; ++Nt)
#pragma unroll
    for (int c = 0; c < 3; ++c) {
        unsigned short eh[8], el[8];
#pragma unroll
        for (int j = 0; j < 8; ++j) {
            int ci = 2 * g + (j >> 2), dx = j & 3;
            int cc = Nt * 16 + col;
            float w = 0.f;
            if (cc < 25 && dx < 3) w = wts[25 + cc * 72 + ci * 9 + c * 3 + dx];
            unsigned int pk = bfsplit_pack(w);
            eh[j] = (unsigned short)(pk & 0xFFFFu);
            el[j] = (unsigned short)(pk >> 16);
        }
#pragma unroll
        for (int q = 0; q < 4; ++q) {
            Bh[Nt][c].u[q] = (unsigned int)eh[2*q] | ((unsigned int)eh[2*q+1] << 16);
            Bl[Nt][c].u[q] = (unsigned int)el[2*q] | ((unsigned int)el[2*q+1] << 16);
        }
    }
    __syncthreads();

    const float* bias = wts;
#pragma unroll
    for (int m = 0; m < 4; ++m) {
        const int M = wave * 4 + m;
        const int py = M >> 1;
        const int pxx = (M & 1) * 16 + col;    // this lane's A-row pixel
        FU Ah[3], Al[3];
#pragma unroll
        for (int c = 0; c < 3; ++c) {
            const unsigned int* r0 = &hal[2 * g][py + c][pxx];
            const unsigned int* r1 = &hal[2 * g + 1][py + c][pxx];
            unsigned int q0 = r0[0], q1 = r0[1], q2 = r0[2], q3 = r0[3];
            unsigned int q4 = r1[0], q5 = r1[1], q6 = r1[2], q7 = r1[3];
            Ah[c].u[0] = __builtin_amdgcn_perm(q1, q0, 0x05040100u);
            Ah[c].u[1] = __builtin_amdgcn_perm(q3, q2, 0x05040100u);
            Ah[c].u[2] = __builtin_amdgcn_perm(q5, q4, 0x05040100u);
            Ah[c].u[3] = __builtin_amdgcn_perm(q7, q6, 0x05040100u);
            Al[c].u[0] = __builtin_amdgcn_perm(q1, q0, 0x07060302u);
            Al[c].u[1] = __builtin_amdgcn_perm(q3, q2, 0x07060302u);
            Al[c].u[2] = __builtin_amdgcn_perm(q5, q4, 0x07060302u);
            Al[c].u[3] = __builtin_amdgcn_perm(q7, q6, 0x07060302u);
        }
#pragma unroll
        for (int Nt = 0; Nt < 2; ++Nt) {
            f32x4 acc = {0.f, 0.f, 0.f, 0.f};
#pragma unroll
            for (int c = 0; c < 3; ++c) {
                acc = __builtin_amdgcn_mfma_f32_16x16x32_bf16(Ah[c].v, Bh[Nt][c].v, acc, 0, 0, 0);
                acc = __builtin_amdgcn_mfma_f32_16x16x32_bf16(Al[c].v, Bh[Nt][c].v, acc, 0, 0, 0);
                acc = __builtin_amdgcn_mfma_f32_16x16x32_bf16(Ah[c].v, Bl[Nt][c].v, acc, 0, 0, 0);
            }
            const int co = Nt * 16 + col;
            if (co < 25) {
                float bs = bias[co];
#pragma unroll
                for (int r = 0; r < 4; ++r)
                    outb[wave][m * 16 + g * 4 + r][co] = acc[r] + bs;
            }
        }
    }
    __syncthreads();
    // finalize: each lane owns one pixel; sigmoid+normalize, then bilinear sample
    {
        const int pl = lane;
        const int Ml = pl >> 4, rd = pl & 15;
        const int M = wave * 4 + Ml;
        const int py = M >> 1;
        const int pxx = (M & 1) * 16 + rd;
        const int gy = y0 + py, gx = x0 + pxx;
        float v[25];
#pragma unroll
        for (int c = 0; c < 25; ++c) v[c] = outb[wave][pl][c];
        float w9[9], s = 0.f;
#pragma unroll
        for (int k = 0; k < 9; ++k) { w9[k] = 1.f / (1.f + __expf(-v[k])); s += w9[k]; }
        const float inv = 1.f / (s + 1e-8f);
        float out = 0.f;
#pragma unroll
        for (int k = 0; k < 9; ++k) {
            float oy = 0.f, ox = 0.f;
            if (k != 4) {
                int kp = (k < 4) ? k : (k - 1);
                oy = v[9 + 2 * kp];
                ox = v[10 + 2 * kp];
            }
            float ys = (float)(gy + k / 3 - 1) + oy;
            float xs = (float)(gx + k % 3 - 1) + ox;
            float yf = floorf(ys), xf = floorf(xs);
            float wy = ys - yf, wx = xs - xf;
            int yi = (int)yf, xi = (int)xf;
            float v00 = samp(src, yi, xi);
            float v01 = samp(src, yi, xi + 1);
            float v10 = samp(src, yi + 1, xi);
            float v11 = samp(src, yi + 1, xi + 1);
            float sv = v00 * (1.f - wy) * (1.f - wx) + v01 * (1.f - wy) * wx
                     + v10 * wy * (1.f - wx) + v11 * wy * wx;
            out = fmaf(w9[k] * inv, sv, out);
        }
        dst[gy * WW + gx] = out;
    }
}

// ---------------- tail (unchanged) ----------------
__global__ __launch_bounds__(256) void tail1(
        const void* __restrict__ attn, const int* __restrict__ flagp,
        const float* __restrict__ tw, const float* __restrict__ feats,
        float* __restrict__ a1) {
    const int bf = *flagp;
    const int p = blockIdx.x * 256 + threadIdx.x;
    float x3[3] = { feats[3 * HWSZ + p], feats[4 * HWSZ + p], feats[5 * HWSZ + p] };
    float sf[6];
#pragma unroll
    for (int j = 0; j < 6; ++j) {
        float v = tw[j * 3 + 0] * x3[0] + tw[j * 3 + 1] * x3[1] + tw[j * 3 + 2] * x3[2];
        v = v * tw[18 + j] + tw[24 + j];
        sf[j] = (v >= 0.0f) ? v : 0.2f * v;
    }
#pragma unroll
    for (int c = 0; c < 22; ++c) {
        float x = (c < 16) ? ld_in(attn, (long long)c * HWSZ + p, bf) : sf[c - 16];
        a1[c * HWSZ + p] = fmaf(x, tw[32 + c], tw[54 + c]);
    }
}

__global__ __launch_bounds__(256) void tail2(
        const float* __restrict__ tw, const float* __restrict__ a1,
        float* __restrict__ a11, float* __restrict__ a21, float* __restrict__ agg) {
    __shared__ float tile[10][34];
    const int bx = blockIdx.x % 38, by = blockIdx.x / 38;
    const int x0 = bx * 32, y0 = by * 8;
    const int lx = threadIdx.x % 32, ly = threadIdx.x / 32;
    float acc1[11], acc2[11];
#pragma unroll
    for (int j = 0; j < 11; ++j) { acc1[j] = tw[538 + j]; acc2[j] = tw[791 + j]; }
    for (int c = 0; c < 22; ++c) {
        __syncthreads();
        for (int idx = threadIdx.x; idx < 340; idx += 256) {
            int r = idx / 34, cc = idx % 34;
            int gy = y0 - 1 + r, gx = x0 - 1 + cc;
            tile[r][cc] = (gy >= 0 && gy < HH && gx >= 0 && gx < WW)
                          ? a1[c * HWSZ + gy * WW + gx] : 0.0f;
        }
        __syncthreads();
        float a1c = tile[ly + 1][lx + 1];
        float a2c = tw[274 + c];
#pragma unroll
        for (int dy = 0; dy < 3; ++dy)
#pragma unroll
            for (int dx = 0; dx < 3; ++dx)
                a2c = fmaf(tile[ly + dy][lx + dx], tw[76 + c * 9 + dy * 3 + dx], a2c);
#pragma unroll
        for (int j = 0; j < 11; ++j) {
            acc1[j] = fmaf(a1c, tw[296 + j * 22 + c], acc1[j]);
            acc2[j] = fmaf(a2c, tw[549 + j * 22 + c], acc2[j]);
        }
    }
    const int p = (y0 + ly) * WW + x0 + lx;
    float s = 0.0f, mx = -1e30f;
#pragma unroll
    for (int j = 0; j < 11; ++j) {
        a11[j * HWSZ + p] = acc1[j];
        a21[j * HWSZ + p] = acc2[j];
        s += acc1[j] + acc2[j];
        mx = fmaxf(mx, fmaxf(acc1[j], acc2[j]));
    }
    agg[p] = s * (1.0f / 22.0f);
    agg[HWSZ + p] = mx;
}

__global__ __launch_bounds__(256) void tail3(
        const int* __restrict__ flagp, const float* __restrict__ tw,
        const float* __restrict__ feats,
        const float* __restrict__ a11, const float* __restrict__ a21,
        const float* __restrict__ agg, void* __restrict__ out) {
    __shared__ float t0[10][34], t1[10][34];
    const int bx = blockIdx.x % 38, by = blockIdx.x / 38;
    const int x0 = bx * 32, y0 = by * 8;
    for (int idx = threadIdx.x; idx < 340; idx += 256) {
        int r = idx / 34, cc = idx % 34;
        int gy = y0 - 1 + r, gx = x0 - 1 + cc;
        bool ok = (gy >= 0 && gy < HH && gx >= 0 && gx < WW);
        t0[r][cc] = ok ? agg[gy * WW + gx] : 0.0f;
        t1[r][cc] = ok ? agg[HWSZ + gy * WW + gx] : 0.0f;
    }
    __syncthreads();
    const int lx = threadIdx.x % 32, ly = threadIdx.x / 32;
    float s0 = tw[838], s1 = tw[839];
#pragma unroll
    for (int dy = 0; dy < 3; ++dy)
#pragma unroll
        for (int dx = 0; dx < 3; ++dx) {
            float v0 = t0[ly + dy][lx + dx], v1 = t1[ly + dy][lx + dx];
            s0 = fmaf(v0, tw[802 + 0 * 18 + 0 * 9 + dy * 3 + dx], s0);
            s0 = fmaf(v1, tw[802 + 0 * 18 + 1 * 9 + dy * 3 + dx], s0);
            s1 = fmaf(v0, tw[802 + 1 * 18 + 0 * 9 + dy * 3 + dx], s1);
            s1 = fmaf(v1, tw[802 + 1 * 18 + 1 * 9 + dy * 3 + dx], s1);
        }
    float sg0 = 1.0f / (1.0f + __expf(-s0));
    float sg1 = 1.0f / (1.0f + __expf(-s1));
    const int p = (y0 + ly) * WW + x0 + lx;
    float at3[3] = { tw[873], tw[874], tw[875] };
#pragma unroll
    for (int j = 0; j < 11; ++j) {
        float at = a11[j * HWSZ + p] * sg0 + a21[j * HWSZ + p] * sg1;
#pragma unroll
        for (int i = 0; i < 3; ++i) at3[i] = fmaf(at, tw[840 + i * 11 + j], at3[i]);
    }
    float o = feats[3 * HWSZ + p] * at3[0] + feats[4 * HWSZ + p] * at3[1]
            + feats[5 * HWSZ + p] * at3[2];
    int bf = *flagp;
    if (bf) ((__hip_bfloat16*)out)[p] = __float2bfloat16(o);
    else    ((float*)out)[p] = o;
}

// ---------------- host ----------------
extern "C" void kernel_launch(void* const* d_in, const int* in_sizes, int n_in,
                              void* d_out, int out_size, void* d_ws, size_t ws_size,
                              hipStream_t stream) {
    (void)in_sizes; (void)n_in; (void)out_size; (void)ws_size;
    float* WSF = (float*)d_ws;
    const int* flagp = (const int*)d_ws;
    float* cw   = WSF + WS_CW;
    float* tw   = WSF + WS_TW;
    float* FB   = WSF + WS_FB;             // 7 planes
    float* A1   = FB + 7 * HWSZ;           // 22 planes
    float* A11  = A1 + 22 * HWSZ;          // 11 planes
    float* A21  = A11 + 11 * HWSZ;         // 11 planes
    float* AGG  = A21 + 11 * HWSZ;         // 2 planes

    prep_small<<<32, 256, 0, stream>>>(d_in[1],
        d_in[4], d_in[5], d_in[6], d_in[7],
        d_in[8], d_in[9], d_in[10], d_in[11], d_in[12],
        d_in[13], d_in[14], d_in[15], d_in[16],
        d_in[17], d_in[18], d_in[19], d_in[20],
        d_in[21], d_in[22], d_in[23], d_in[24], WSF);
    prep_feat<<<(HWSZ + 255) / 256, 256, 0, stream>>>(d_in[0], flagp, FB + 6 * HWSZ);

    for (int t = 0; t < 6; ++t) {
        const float* src = (t == 0) ? (FB + 6 * HWSZ) : (FB + (t - 1) * HWSZ);
        dcn_fused<<<44 * 38, 256, 0, stream>>>(d_in[1], flagp, cw + t * 1825, src, FB + t * HWSZ, t);
    }
    tail1<<<HWSZ / 256, 256, 0, stream>>>(d_in[2], flagp, tw, FB, A1);
    tail2<<<44 * 38, 256, 0, stream>>>(tw, A1, A11, A21, AGG);
    tail3<<<44 * 38, 256, 0, stream>>>(flagp, tw, FB, A11, A21, AGG, d_out);
}